// Round 1
// baseline (322.795 us; speedup 1.0000x reference)
//
#include <hip/hip_runtime.h>
#include <stdint.h>

#define M_TOK 32768
#define N_OUT 1024
#define K_IN  1024

#define BM 128
#define BN 128
#define BK 32
#define LDT 40   // padded LDS row stride in shorts: 80 B -> bank stride 20, no 8-way alias

typedef __bf16 bf16_t;
typedef bf16_t bf16x8 __attribute__((ext_vector_type(8)));
typedef bf16_t bf16x4 __attribute__((ext_vector_type(4)));
typedef float  floatx4 __attribute__((ext_vector_type(4)));

// sign(w) -> bf16 {+1,-1,0}, 4 elements per thread (unchanged; wb is 2 MB, L2-resident)
__global__ void cvt_w_kernel(const float* __restrict__ w, unsigned short* __restrict__ wb) {
    size_t i = (size_t)blockIdx.x * blockDim.x + threadIdx.x;   // group of 4
    const float4* wv = (const float4*)(w + i * 4);
    float4 a = wv[0];
    unsigned short s0 = (a.x > 0.f) ? 0x3F80u : ((a.x < 0.f) ? 0xBF80u : 0u);
    unsigned short s1 = (a.y > 0.f) ? 0x3F80u : ((a.y < 0.f) ? 0xBF80u : 0u);
    unsigned short s2 = (a.z > 0.f) ? 0x3F80u : ((a.z < 0.f) ? 0xBF80u : 0u);
    unsigned short s3 = (a.w > 0.f) ? 0x3F80u : ((a.w < 0.f) ? 0xBF80u : 0u);
    uint2 o;
    o.x = (unsigned int)s0 | ((unsigned int)s1 << 16);
    o.y = (unsigned int)s2 | ((unsigned int)s3 << 16);
    *(uint2*)(wb + i * 4) = o;
}

// C[M][N] = bf16(X[M][K]) * B[N][K]^T + bias, C fp32.
// Fused: X is fp32; conversion to bf16 happens in-register during A staging.
// Reg-staged A and B -> padded LDS (kills the 8.4M bank-conflict cycles of the
// old unpadded global_load_lds layout). T14: next tile's global loads issued
// during current tile's MFMA phase; vmcnt wait lands at the ds_write after the
// next barrier, hiding L2/HBM latency under compute.
__global__ __launch_bounds__(256) void gemm_sign_fused(
    const float* __restrict__ X,            // [M][K] fp32
    const unsigned short* __restrict__ B,   // [N][K] bf16 bits (= sign(W))
    const float* __restrict__ bias,         // [N]
    float* __restrict__ C)                  // [M][N]
{
    __shared__ __align__(16) unsigned short sA[BM * LDT];   // 10 KB
    __shared__ __align__(16) unsigned short sB[BN * LDT];   // 10 KB

    const int t    = threadIdx.x;
    // XCD-aware swizzle (unchanged): XCD = linear_block_id % 8 round-robin;
    // each XCD walks one bm strip through all 8 bn values back-to-back so the
    // A strip (512 KB fp32) stays resident in that XCD's L2 across bn passes.
    const int b    = blockIdx.x;
    const int bm   = ((b >> 6) << 3) + (b & 7);   // 0..255
    const int bn   = (b >> 3) & 7;                // 0..7

    const int wave = t >> 6;
    const int lane = t & 63;
    const int wm   = wave >> 1;       // 0..1
    const int wn   = wave & 1;        // 0..1
    const int lrow = lane & 15;       // m (A) / n (B) / col (C)
    const int quad = lane >> 4;       // 0..3

    // --- A staging geometry: 128x32 fp32 tile = 4 chunks of (256 thr x float4)
    //   chunk c: row = c*32 + t/8, col = (t&7)*4 floats  -> 8 lanes cover 128 B/row
    const int arow = t >> 3;                 // 0..31
    const int acol = (t & 7) * 4;            // float index within BK
    const float* gA = X + (size_t)(bm * BM + arow) * K_IN + acol;
    unsigned short* sAw = sA + arow * LDT + acol;   // byte = row*80 + (t&7)*8, 8B-aligned

    // --- B staging geometry: 128x32 bf16 tile = 2 chunks of (256 thr x 16B)
    //   chunk c: row = c*64 + t/4, col = (t&3)*8 shorts
    const int brow = t >> 2;                 // 0..63
    const int bcol = (t & 3) * 8;            // short index within BK
    const unsigned short* gB = B + (size_t)(bn * BN + brow) * K_IN + bcol;
    unsigned short* sBw = sB + brow * LDT + bcol;   // byte = row*80 + (t&3)*16, 16B-aligned

    floatx4 aR[4];
    bf16x8  bR[2];

    auto load_tile = [&](int kb) {
#pragma unroll
        for (int c = 0; c < 4; ++c)
            aR[c] = *(const floatx4*)(gA + (size_t)c * 32 * K_IN + kb);
#pragma unroll
        for (int c = 0; c < 2; ++c)
            bR[c] = *(const bf16x8*)(gB + (size_t)c * 64 * K_IN + kb);
    };

    floatx4 acc[4][4] = {};

    load_tile(0);

    for (int kt = 0; kt < K_IN / BK; ++kt) {
        __syncthreads();   // all waves done reading LDS from previous iter

        // write staged regs to LDS (fp32 -> bf16 RNE for A, raw copy for B)
#pragma unroll
        for (int c = 0; c < 4; ++c) {
            bf16x4 h = __builtin_convertvector(aR[c], bf16x4);
            *(bf16x4*)(sAw + c * 32 * LDT) = h;
        }
#pragma unroll
        for (int c = 0; c < 2; ++c)
            *(bf16x8*)(sBw + c * 64 * LDT) = bR[c];

        __syncthreads();   // staged tile visible

        // T14: issue next tile's global loads now; they complete during the
        // MFMA phase below and are consumed at next iter's ds_write.
        if (kt + 1 < K_IN / BK) load_tile((kt + 1) * BK);

        bf16x8 af[4], bfr[4];
#pragma unroll
        for (int i = 0; i < 4; ++i)
            af[i] = *(const bf16x8*)(sA + (wm * 64 + i * 16 + lrow) * LDT + quad * 8);
#pragma unroll
        for (int j = 0; j < 4; ++j)
            bfr[j] = *(const bf16x8*)(sB + (wn * 64 + j * 16 + lrow) * LDT + quad * 8);

#pragma unroll
        for (int i = 0; i < 4; ++i)
#pragma unroll
            for (int j = 0; j < 4; ++j)
                acc[i][j] = __builtin_amdgcn_mfma_f32_16x16x32_bf16(af[i], bfr[j], acc[i][j], 0, 0, 0);
    }

    // epilogue: C[row][col] = acc + bias[col]  (layout verified by prior passes)
    const int crow_base = bm * BM + wm * 64;
    const int ccol_base = bn * BN + wn * 64;
#pragma unroll
    for (int j = 0; j < 4; ++j) {
        const int col = ccol_base + j * 16 + lrow;
        const float bv = bias[col];
#pragma unroll
        for (int i = 0; i < 4; ++i) {
            const int rbase = crow_base + i * 16 + quad * 4;
#pragma unroll
            for (int r = 0; r < 4; ++r) {
                C[(size_t)(rbase + r) * N_OUT + col] = acc[i][j][r] + bv;
            }
        }
    }
}

extern "C" void kernel_launch(void* const* d_in, const int* in_sizes, int n_in,
                              void* d_out, int out_size, void* d_ws, size_t ws_size,
                              hipStream_t stream) {
    const float* x    = (const float*)d_in[0];   // [32768,1024]
    const float* w    = (const float*)d_in[1];   // [1024,1024]
    const float* bias = (const float*)d_in[2];   // [1024]
    float* out        = (float*)d_out;           // [32768,1024]

    unsigned short* wb = (unsigned short*)d_ws;  // 2 MB sign(W) in bf16

    cvt_w_kernel<<<1024, 256, 0, stream>>>(w, wb);
    gemm_sign_fused<<<(M_TOK / BM) * (N_OUT / BN), 256, 0, stream>>>(x, wb, bias, out);
}

// Round 2
// 302.702 us; speedup vs baseline: 1.0664x; 1.0664x over previous
//
#include <hip/hip_runtime.h>
#include <stdint.h>

#define M_TOK 32768
#define N_OUT 1024
#define K_IN  1024

#define BM 256
#define BN 256
#define BK 64

typedef __bf16 bf16_t;
typedef bf16_t bf16x8 __attribute__((ext_vector_type(8)));
typedef float  floatx4 __attribute__((ext_vector_type(4)));

__device__ __forceinline__ unsigned short f2bf(float f) {
    // round-to-nearest-even fp32 -> bf16
    uint32_t u = __float_as_uint(f);
    u += 0x7FFFu + ((u >> 16) & 1u);
    return (unsigned short)(u >> 16);
}

// x fp32 -> bf16, 8 elements per thread
__global__ void cvt_x_kernel(const float* __restrict__ x, unsigned short* __restrict__ xb) {
    size_t i = (size_t)blockIdx.x * blockDim.x + threadIdx.x;   // group of 8 floats
    const float4* xv = (const float4*)(x + i * 8);
    float4 a = xv[0];
    float4 b = xv[1];
    unsigned int p0 = (unsigned int)f2bf(a.x) | ((unsigned int)f2bf(a.y) << 16);
    unsigned int p1 = (unsigned int)f2bf(a.z) | ((unsigned int)f2bf(a.w) << 16);
    unsigned int p2 = (unsigned int)f2bf(b.x) | ((unsigned int)f2bf(b.y) << 16);
    unsigned int p3 = (unsigned int)f2bf(b.z) | ((unsigned int)f2bf(b.w) << 16);
    uint4 o; o.x = p0; o.y = p1; o.z = p2; o.w = p3;
    *(uint4*)(xb + i * 8) = o;
}

// sign(w) -> bf16 {+1,-1,0}, 4 elements per thread
__global__ void cvt_w_kernel(const float* __restrict__ w, unsigned short* __restrict__ wb) {
    size_t i = (size_t)blockIdx.x * blockDim.x + threadIdx.x;   // group of 4
    const float4* wv = (const float4*)(w + i * 4);
    float4 a = wv[0];
    unsigned short s0 = (a.x > 0.f) ? 0x3F80u : ((a.x < 0.f) ? 0xBF80u : 0u);
    unsigned short s1 = (a.y > 0.f) ? 0x3F80u : ((a.y < 0.f) ? 0xBF80u : 0u);
    unsigned short s2 = (a.z > 0.f) ? 0x3F80u : ((a.z < 0.f) ? 0xBF80u : 0u);
    unsigned short s3 = (a.w > 0.f) ? 0x3F80u : ((a.w < 0.f) ? 0xBF80u : 0u);
    uint2 o;
    o.x = (unsigned int)s0 | ((unsigned int)s1 << 16);
    o.y = (unsigned int)s2 | ((unsigned int)s3 << 16);
    *(uint2*)(wb + i * 4) = o;
}

// async 16B global -> LDS (direct, no VGPR round trip)
__device__ __forceinline__ void stage16(const unsigned short* g, unsigned short* l) {
    __builtin_amdgcn_global_load_lds(
        (const __attribute__((address_space(1))) unsigned int*)g,
        (__attribute__((address_space(3))) unsigned int*)l, 16, 0, 0);
}

// ---------------- 8-phase 256x256 template (T1+T2+T3+T4+T5) ----------------
// LDS: sA[2][2][128][64] bf16 (buf, half, row, granule-swizzled) + sB same.
// Swizzle: within a row (8 granules of 16 B), physical granule = logical ^ (row&7).
//   gload_lds writes linearly -> the SOURCE global address is pre-swizzled;
//   ds_read applies the same XOR -> fragment reads are 2-way (= free) on banks.
// Schedule (iter i: t0=2i from buf0, t1=2i+1 from buf1):
//   ph1: LOAD af[m-half0],bf[n0,n1](t0); stage A1(t1)->buf1 ; MFMA q(0,0)
//   ph2: LOAD bf[n2,n3](t0)           ; stage B0(t1)->buf1 ; MFMA q(0,1)
//   ph3: LOAD af[m-half1](t0)         ; stage B1(t1)->buf1 ; MFMA q(1,0)
//   ph4:                                stage A0(t0+2)->buf0; MFMA q(1,1); vmcnt(2)
//   ph5-8: same on t1/buf1, staging A1,B0,B1(t0+2)->buf0 and A0(t1+2)->buf1; vmcnt(2) at ph8
// Safety: every LDS region is restaged only after the closing barrier of the
// phase containing its last read; every region is read only after a counted
// vmcnt covering its 2 loads + a barrier. vmcnt never drains to 0 in the loop.

#define PH_OPEN() do { asm volatile("" ::: "memory"); \
    __builtin_amdgcn_s_barrier(); \
    __builtin_amdgcn_s_setprio(1); } while(0)

#define PH_CLOSE() do { __builtin_amdgcn_s_setprio(0); \
    asm volatile("s_waitcnt lgkmcnt(0)" ::: "memory"); \
    __builtin_amdgcn_s_barrier(); } while(0)

#define PH_CLOSE_VM() do { __builtin_amdgcn_s_setprio(0); \
    asm volatile("s_waitcnt vmcnt(2)" ::: "memory"); \
    asm volatile("s_waitcnt lgkmcnt(0)" ::: "memory"); \
    __builtin_amdgcn_s_barrier(); } while(0)

#define STAGE_A(p,h,kt) do { \
    const unsigned short* _g = gAs + (size_t)((h) * 128) * K_IN + (kt) * BK; \
    unsigned short* _l = lAs + (p) * 16384 + (h) * 8192; \
    stage16(_g, _l); \
    stage16(_g + (size_t)(64 * K_IN), _l + 4096); \
} while(0)

#define STAGE_B(p,h,kt) do { \
    const unsigned short* _g = gBs + (size_t)((h) * 128) * K_IN + (kt) * BK; \
    unsigned short* _l = lBs + (p) * 16384 + (h) * 8192; \
    stage16(_g, _l); \
    stage16(_g + (size_t)(64 * K_IN), _l + 4096); \
} while(0)

#define LOAD_A(p,mh) do { _Pragma("unroll") \
    for (int mi = 0; mi < 4; ++mi) { \
        const unsigned short* _b = rA + (p) * 16384 + ((mh) * 64 + mi * 16) * 64; \
        af[mi][0] = *(const bf16x8*)(_b + gp0 * 8); \
        af[mi][1] = *(const bf16x8*)(_b + gp1 * 8); \
    } } while(0)

#define LOAD_B(p,nh) do { _Pragma("unroll") \
    for (int ni = 0; ni < 2; ++ni) { \
        const unsigned short* _b = rB + (p) * 16384 + ((nh) * 32 + ni * 16) * 64; \
        bf[(nh) * 2 + ni][0] = *(const bf16x8*)(_b + gp0 * 8); \
        bf[(nh) * 2 + ni][1] = *(const bf16x8*)(_b + gp1 * 8); \
    } } while(0)

#define MFMA_Q(mh,nh) do { _Pragma("unroll") \
    for (int mi = 0; mi < 4; ++mi) { _Pragma("unroll") \
        for (int ni = 0; ni < 2; ++ni) { \
            acc[(mh)*4+mi][(nh)*2+ni] = __builtin_amdgcn_mfma_f32_16x16x32_bf16( \
                af[mi][0], bf[(nh)*2+ni][0], acc[(mh)*4+mi][(nh)*2+ni], 0, 0, 0); \
            acc[(mh)*4+mi][(nh)*2+ni] = __builtin_amdgcn_mfma_f32_16x16x32_bf16( \
                af[mi][1], bf[(nh)*2+ni][1], acc[(mh)*4+mi][(nh)*2+ni], 0, 0, 0); \
        } } } while(0)

__global__ __launch_bounds__(512, 2) void gemm8p(
    const unsigned short* __restrict__ A,   // [M][K] bf16 bits
    const unsigned short* __restrict__ B,   // [N][K] bf16 bits (= sign(W))
    const float* __restrict__ bias,         // [N]
    float* __restrict__ C)                  // [M][N]
{
    extern __shared__ unsigned short lds[];     // 128 KiB
    unsigned short* sA = lds;                   // 32768 shorts (64 KB)
    unsigned short* sB = lds + 32768;

    const int t = threadIdx.x;
    const int b = blockIdx.x;
    // XCD swizzle: nwg=512 (%8==0): each XCD owns 64 consecutive wg = 16 bm x 4 bn
    const int wg = ((b & 7) << 6) + (b >> 3);
    const int bm = wg >> 2;       // 0..127
    const int bn = wg & 3;        // 0..3

    const int w    = t >> 6;      // 0..7
    const int lane = t & 63;
    const int wm   = w >> 2;      // 0..1  (A half / C row half)
    const int wn   = w & 3;       // 0..3  (C col quarter)
    const int lrow = lane & 15;
    const int quad = lane >> 4;

    // --- staging addressing: wave w round rd covers rows rd*64 + w*8 + lane/8,
    //     granule (lane&7); pre-swizzled global source granule = (lane&7)^(lane>>3)
    //     (row&7 == lane>>3 since rd*64 and w*8 are multiples of 8)
    const int srow = (w << 3) + (lane >> 3);
    const int glog = (lane & 7) ^ (lane >> 3);
    const unsigned short* gAs = A + (size_t)(bm * BM + srow) * K_IN + glog * 8;
    const unsigned short* gBs = B + (size_t)(bn * BN + srow) * K_IN + glog * 8;
    unsigned short* lAs = sA + t * 8;   // = w*512 + lane*8  (linear dest)
    unsigned short* lBs = sB + t * 8;

    // --- fragment read bases; read granule = (ks*4+quad) ^ (row&7), row&7==lrow&7
    const unsigned short* rA = sA + wm * 8192 + lrow * 64;
    const unsigned short* rB = sB + (wn >> 1) * 8192 + ((wn & 1) * 64 + lrow) * 64;
    const int gp0 = quad ^ (lrow & 7);        // ks=0
    const int gp1 = (4 + quad) ^ (lrow & 7);  // ks=1

    bf16x8  af[4][2];   // current m-half fragments
    bf16x8  bf[4][2];   // all 4 ni fragments
    floatx4 acc[8][4] = {};

    // prologue: t=0 fully + A0(1); gate t=0 with counted vmcnt (A0(1) stays in flight)
    STAGE_A(0, 0, 0); STAGE_A(0, 1, 0); STAGE_B(0, 0, 0); STAGE_B(0, 1, 0);
    STAGE_A(1, 0, 1);
    asm volatile("s_waitcnt vmcnt(2)" ::: "memory");
    __builtin_amdgcn_s_barrier();

#pragma unroll 1
    for (int i = 0; i < 8; ++i) {
        const int t1 = 2 * i + 1;
        const int e  = (2 * i + 2) & 15;   // wraps harmlessly on last iter (never read)
        const int o  = (2 * i + 3) & 15;
        // ph1
        LOAD_A(0, 0); LOAD_B(0, 0); STAGE_A(1, 1, t1);
        PH_OPEN(); MFMA_Q(0, 0); PH_CLOSE();
        // ph2
        LOAD_B(0, 1); STAGE_B(1, 0, t1);
        PH_OPEN(); MFMA_Q(0, 1); PH_CLOSE();
        // ph3
        LOAD_A(0, 1); STAGE_B(1, 1, t1);
        PH_OPEN(); MFMA_Q(1, 0); PH_CLOSE();
        // ph4 (no ds_reads) — gate t1's 4 half-tiles before ph5 reads them
        STAGE_A(0, 0, e);
        PH_OPEN(); MFMA_Q(1, 1); PH_CLOSE_VM();
        // ph5
        LOAD_A(1, 0); LOAD_B(1, 0); STAGE_A(0, 1, e);
        PH_OPEN(); MFMA_Q(0, 0); PH_CLOSE();
        // ph6
        LOAD_B(1, 1); STAGE_B(0, 0, e);
        PH_OPEN(); MFMA_Q(0, 1); PH_CLOSE();
        // ph7
        LOAD_A(1, 1); STAGE_B(0, 1, e);
        PH_OPEN(); MFMA_Q(1, 0); PH_CLOSE();
        // ph8 — gate e's 4 half-tiles before next iter's ph1 reads them
        STAGE_A(1, 0, o);
        PH_OPEN(); MFMA_Q(1, 1); PH_CLOSE_VM();
    }
    asm volatile("s_waitcnt vmcnt(0)" ::: "memory");   // drain tail prefetches

    // epilogue: C[row][col] = acc + bias[col]
    const int crow0 = bm * BM + wm * 128 + quad * 4;
    const int ccol0 = bn * BN + wn * 64;
#pragma unroll
    for (int ni = 0; ni < 4; ++ni) {
        const int col = ccol0 + ni * 16 + lrow;
        const float bv = bias[col];
#pragma unroll
        for (int mi = 0; mi < 8; ++mi) {
            const int row = crow0 + mi * 16;
#pragma unroll
            for (int r = 0; r < 4; ++r)
                C[(size_t)(row + r) * N_OUT + col] = acc[mi][ni][r] + bv;
        }
    }
}

extern "C" void kernel_launch(void* const* d_in, const int* in_sizes, int n_in,
                              void* d_out, int out_size, void* d_ws, size_t ws_size,
                              hipStream_t stream) {
    const float* x    = (const float*)d_in[0];   // [32768,1024]
    const float* w    = (const float*)d_in[1];   // [1024,1024]
    const float* bias = (const float*)d_in[2];   // [1024]
    float* out        = (float*)d_out;           // [32768,1024]

    unsigned short* xb = (unsigned short*)d_ws;                                      // 64 MB
    unsigned short* wb = (unsigned short*)((char*)d_ws + (size_t)M_TOK * K_IN * 2);  // 2 MB

    static bool attr_set = false;
    if (!attr_set) {
        hipFuncSetAttribute((const void*)gemm8p,
                            hipFuncAttributeMaxDynamicSharedMemorySize, 131072);
        attr_set = true;
    }

    cvt_x_kernel<<<16384, 256, 0, stream>>>(x, xb);
    cvt_w_kernel<<<1024, 256, 0, stream>>>(w, wb);
    gemm8p<<<(M_TOK / BM) * (N_OUT / BN), 512, 131072, stream>>>(xb, wb, bias, out);
}